// Round 2
// baseline (6264.681 us; speedup 1.0000x reference)
//
#include <hip/hip_runtime.h>
#include <stdint.h>
#include <stddef.h>

#define NROWS 8192
#define NCOLS 8192       // K dimension = noise-matrix column count
#define DDIM  1024

typedef float  f32x4 __attribute__((ext_vector_type(4)));
typedef _Float16 f16x8 __attribute__((ext_vector_type(8)));

#if __has_builtin(__builtin_amdgcn_exp2f)
#define EXP2F(x) __builtin_amdgcn_exp2f(x)
#else
#define EXP2F(x) exp2f(x)
#endif
#if __has_builtin(__builtin_amdgcn_logf)
#define LOG2F(x) __builtin_amdgcn_logf(x)     // v_log_f32 = log2
#else
#define LOG2F(x) log2f(x)
#endif
#if __has_builtin(__builtin_amdgcn_sqrtf)
#define SQRTF(x) __builtin_amdgcn_sqrtf(x)
#else
#define SQRTF(x) sqrtf(x)
#endif

// ---------------- Threefry-2x32, key = (0, 42) (jax.random.key(42)) ---------
__device__ __forceinline__ uint32_t rotl32(uint32_t x, uint32_t r){
  return (x << r) | (x >> (32u - r));
}

__device__ __forceinline__ void threefry2x32(uint32_t x0, uint32_t x1,
                                             uint32_t& o0, uint32_t& o1){
  const uint32_t k0 = 0u, k1 = 42u;
  const uint32_t k2 = k0 ^ k1 ^ 0x1BD11BDAu;
  x0 += k0; x1 += k1;
#define TF_R(r) { x0 += x1; x1 = rotl32(x1, r); x1 ^= x0; }
  TF_R(13) TF_R(15) TF_R(26) TF_R(6)
  x0 += k1; x1 += k2 + 1u;
  TF_R(17) TF_R(29) TF_R(16) TF_R(24)
  x0 += k2; x1 += k0 + 2u;
  TF_R(13) TF_R(15) TF_R(26) TF_R(6)
  x0 += k0; x1 += k1 + 3u;
  TF_R(17) TF_R(29) TF_R(16) TF_R(24)
  x0 += k1; x1 += k2 + 4u;
  TF_R(13) TF_R(15) TF_R(26) TF_R(6)
  x0 += k2; x1 += k0 + 5u;
#undef TF_R
  o0 = x0; o1 = x1;
}

// Partitionable-threefry element: flat index f -> E' = exp(2*normal)*2^-4.
__device__ __forceinline__ float elemE(uint32_t f){
  uint32_t o0, o1;
  threefry2x32(0u, f, o0, o1);
  const uint32_t b = o0 ^ o1;
  float u = __uint_as_float((b >> 9) | 0x3F800000u) - 1.0f;   // [0,1)
  const float lo = -0.99999994f;                              // nextafter(-1,0)
  float v = fmaf(u, 2.0f, lo);
  v = fmaxf(v, lo);
  const float t1 = fmaf(-v, v, 1.0f);                         // 1 - v^2
  float w = LOG2F(t1) * (-0.69314718f);                       // -ln(1-v^2)
  float p;
  if (w < 5.0f){
    w -= 2.5f;
    p =              3.97426473e-08f;
    p = fmaf(p, w,   4.85465e-07f);
    p = fmaf(p, w,  -4.98283e-06f);
    p = fmaf(p, w,  -6.21053e-06f);
    p = fmaf(p, w,   3.09120e-04f);
    p = fmaf(p, w,  -1.77290e-03f);
    p = fmaf(p, w,  -5.90817e-03f);
    p = fmaf(p, w,   3.48803163e-01f);
    p = fmaf(p, w,   2.12331355e+00f);
  } else {
    w = SQRTF(w) - 3.0f;
    p =             -2.83147363e-04f;
    p = fmaf(p, w,   1.42765560e-04f);
    p = fmaf(p, w,   1.90825981e-03f);
    p = fmaf(p, w,  -5.19500608e-03f);
    p = fmaf(p, w,   8.11688602e-03f);
    p = fmaf(p, w,  -1.07798386e-02f);
    p = fmaf(p, w,   1.33487061e-02f);
    p = fmaf(p, w,   1.41658096e+00f);
    p = fmaf(p, w,   4.00643396e+00f);
  }
  const float m = p * v;                         // sqrt(2)*erfinv(v) ~ N(0,1)
  return EXP2F(fmaf(m, 2.8853900817779268f, -4.0f)); // exp(2m)*2^-4
}

__device__ __forceinline__ uint16_t f2h(float a){
  union { _Float16 h; uint16_t u; } c; c.h = (_Float16)a; return c.u;
}

// ---------------- transpose: x [8192][1024] f32 -> xT f16 -------------------
__global__ __launch_bounds__(256) void transpose_cast(const float* __restrict__ x,
                                                      uint16_t* __restrict__ xT){
  __shared__ float tile[32][33];
  const int tx = threadIdx.x & 31;
  const int ty = threadIdx.x >> 5;          // 0..7
  const int dcol = blockIdx.x * 32;
  const int nrow = blockIdx.y * 32;
  #pragma unroll
  for (int r = 0; r < 32; r += 8)
    tile[ty + r][tx] = x[(size_t)(nrow + ty + r) * DDIM + dcol + tx];
  __syncthreads();
  #pragma unroll
  for (int r = 0; r < 32; r += 8)
    xT[(size_t)(dcol + ty + r) * NROWS + nrow + tx] = f2h(tile[tx][ty + r]);
}

// ---------------- fallback gen (chunked workspace) --------------------------
__global__ __launch_bounds__(256) void gen_rows(uint16_t* __restrict__ P,
                                                float* __restrict__ S, int row0){
  const int gi = row0 + blockIdx.x;
  const uint32_t base = (uint32_t)gi * 8192u;
  const int t = threadIdx.x;
  uint16_t* __restrict__ prow = P + (size_t)blockIdx.x * NCOLS;
  float acc = 0.0f;
  #pragma unroll
  for (int g = 0; g < 4; ++g){
    const uint32_t j0 = (uint32_t)(g * 2048) + ((uint32_t)t << 3);
    float e[8];
    #pragma unroll
    for (int i = 0; i < 8; ++i){ e[i] = elemE(base + j0 + (uint32_t)i); acc += e[i]; }
    f16x8 pk;
    #pragma unroll
    for (int i = 0; i < 8; ++i) pk[i] = (_Float16)e[i];
    *reinterpret_cast<f16x8*>(prow + j0) = pk;
  }
  #pragma unroll
  for (int off = 32; off > 0; off >>= 1) acc += __shfl_down(acc, off, 64);
  __shared__ float sm[4];
  if ((t & 63) == 0) sm[t >> 6] = acc;
  __syncthreads();
  if (t == 0) S[gi] = (sm[0] + sm[1]) + (sm[2] + sm[3]);
}

typedef const __attribute__((address_space(1))) void GAS;
typedef __attribute__((address_space(3))) void LAS;

__device__ __forceinline__ void gload16(const void* g, void* l){
  __builtin_amdgcn_global_load_lds((GAS*)g, (LAS*)l, 16, 0, 0);
}

// ---------------- fallback GEMM (chunked path): 128x128, 1-phase ------------
#define BM 128
#define BN 128
#define BK 64

__global__ __launch_bounds__(256, 3) void gemm_rows(
    const uint16_t* __restrict__ P, const uint16_t* __restrict__ xT,
    const float* __restrict__ S, int row0, float* __restrict__ O)
{
  __shared__ uint16_t smem[16384];      // As[128][64] | Bs[128][64]
  uint16_t* As = smem;
  uint16_t* Bs = smem + 8192;

  const int tid  = threadIdx.x;
  const int lane = tid & 63;
  const int wave = tid >> 6;
  const int wr = (wave >> 1) * 64;
  const int wc = (wave & 1) * 64;
  const int l15 = lane & 15;
  const int lq  = lane >> 4;

  const size_t m0 = (size_t)blockIdx.x * BM;
  const size_t n0 = (size_t)blockIdx.y * BN;

  const int srow = tid >> 3;                    // 0..31
  const int sx   = (tid & 7) ^ (srow & 7);      // swizzled source k-group
  const uint16_t* gA = P  + (m0 + srow) * (size_t)NCOLS + sx * 8;
  const uint16_t* gB = xT + (n0 + srow) * (size_t)NCOLS + sx * 8;

  f32x4 acc[4][4];
  #pragma unroll
  for (int i = 0; i < 4; ++i)
    #pragma unroll
    for (int j = 0; j < 4; ++j)
      #pragma unroll
      for (int q = 0; q < 4; ++q) acc[i][j][q] = 0.0f;

  const int axor = l15 & 7;

  for (int k0 = 0; k0 < NCOLS; k0 += BK){
    #pragma unroll
    for (int r = 0; r < 4; ++r)
      gload16(gA + (size_t)(32 * r) * NCOLS + k0, As + (tid + 256 * r) * 8);
    #pragma unroll
    for (int r = 0; r < 4; ++r)
      gload16(gB + (size_t)(32 * r) * NCOLS + k0, Bs + (tid + 256 * r) * 8);
    __syncthreads();
    #pragma unroll
    for (int ks = 0; ks < 2; ++ks){
      const int kphys = ((lq + 4 * ks) ^ axor) * 8;
      f16x8 af[4], bfrag[4];
      #pragma unroll
      for (int i = 0; i < 4; ++i)
        af[i] = *reinterpret_cast<const f16x8*>(As + (wr + i*16 + l15) * BK + kphys);
      #pragma unroll
      for (int j = 0; j < 4; ++j)
        bfrag[j] = *reinterpret_cast<const f16x8*>(Bs + (wc + j*16 + l15) * BK + kphys);
      #pragma unroll
      for (int i = 0; i < 4; ++i)
        #pragma unroll
        for (int j = 0; j < 4; ++j)
          acc[i][j] = __builtin_amdgcn_mfma_f32_16x16x32_f16(af[i], bfrag[j], acc[i][j], 0, 0, 0);
    }
    __syncthreads();
  }

  #pragma unroll
  for (int i = 0; i < 4; ++i){
    float rinv[4];
    #pragma unroll
    for (int r = 0; r < 4; ++r)
      rinv[r] = 1.0f / S[row0 + m0 + wr + i*16 + lq*4 + r];
    #pragma unroll
    for (int j = 0; j < 4; ++j){
      const size_t col = n0 + wc + j*16 + l15;
      #pragma unroll
      for (int r = 0; r < 4; ++r){
        const size_t row = m0 + wr + i*16 + lq*4 + r;
        O[row * DDIM + col] = acc[i][j][r] * rinv[r];
      }
    }
  }
}

// ===================== FUSED producer/consumer kernel =======================
// Grid = 768 blocks x 256 threads. Role by b%3: 512 gemm blocks + 256 gen.
// Every block uses 48 KB LDS -> exactly 3 blocks/CU (LDS-capped), 12 waves/CU,
// all 768 blocks resident simultaneously => producer always runs => no
// deadlock. Gen blocks emit P in column-chunks of 64 (all 8192 rows), publish
// flags[kc]; gemm blocks gate staging of K-tile kt on flags[kt>>1].
#define FM 128
#define FN 128
#define FK 32
#define FNT (NCOLS / FK)      // 256 K-tiles
#define FBUF 8192             // uint16 elems per buffer (A 4096 | B 4096)
#define CHUNKS 128            // 8192 / 64
#define GENB 256

__device__ __forceinline__ void wait_flag(uint32_t* f, uint32_t target){
  int guard = 0;
  while (__hip_atomic_load(f, __ATOMIC_RELAXED, __HIP_MEMORY_SCOPE_AGENT) < target){
    __builtin_amdgcn_s_sleep(8);
    if (++guard > (1 << 24)) break;   // safety valve: never triggers if correct
  }
  (void)__hip_atomic_load(f, __ATOMIC_ACQUIRE, __HIP_MEMORY_SCOPE_AGENT);
}

__global__ __launch_bounds__(256, 3) void fused_gen_gemm(
    uint16_t* __restrict__ P,          // [8192][8192] f16 (unnormalized E')
    const uint16_t* __restrict__ xT,   // [1024][8192] f16
    float* __restrict__ Spart,         // [8192][128] f32 per-chunk row sums
    uint32_t* flags,                   // [128] chunk completion counters
    float* __restrict__ O)             // [8192][1024] f32
{
  const int b = blockIdx.x;
  const int t = threadIdx.x;

  if (b % 3 == 2){
    // ------------------------- gen role (256 blocks) -------------------------
    const int g  = b / 3;            // 0..255 -> rows [32g, 32g+32)
    const int rl = t >> 3;           // 0..31 local row
    const int c0 = (t & 7) * 8;      // col offset within 64-col chunk
    const int row = g * 32 + rl;
    uint16_t* prow = P + (size_t)row * NCOLS;
    float* srow = Spart + (size_t)row * CHUNKS;
    const uint32_t fb = (uint32_t)row * 8192u;
    for (int kc = 0; kc < CHUNKS; ++kc){
      const uint32_t f0 = fb + (uint32_t)(kc * 64 + c0);
      float e[8]; float acc = 0.0f;
      #pragma unroll
      for (int i = 0; i < 8; ++i){ e[i] = elemE(f0 + (uint32_t)i); acc += e[i]; }
      f16x8 pk;
      #pragma unroll
      for (int i = 0; i < 8; ++i) pk[i] = (_Float16)e[i];
      __builtin_nontemporal_store(pk, reinterpret_cast<f16x8*>(prow + kc * 64 + c0));
      acc += __shfl_down(acc, 4, 8);
      acc += __shfl_down(acc, 2, 8);
      acc += __shfl_down(acc, 1, 8);
      if ((t & 7) == 0) __builtin_nontemporal_store(acc, srow + kc);
      __threadfence();                 // make this thread's stores agent-visible
      __syncthreads();                 // all threads of block fenced
      if (t == 0)
        __hip_atomic_fetch_add(&flags[kc], 1u, __ATOMIC_RELEASE, __HIP_MEMORY_SCOPE_AGENT);
    }
    return;
  }

  // ------------------------- gemm role (512 blocks) --------------------------
  extern __shared__ uint16_t sm[];     // 3 * FBUF uint16 = 48 KB

  // XCD-rank mapping: XCD x = b&7 owns m-panels [8x, 8x+8), all 8 n-tiles,
  // so each P panel is L2-fetched once per chip. Rank l = gemm index within
  // this XCD's dispatch sequence (skipping gen blocks, which are q ≡ rx mod 3).
  const int x  = b & 7;
  const int q  = b >> 3;               // 0..95
  const int rx = ((2 - (x % 3)) * 2) % 3;
  const int ngen = (q > rx) ? ((q - rx - 1) / 3 + 1) : 0;
  const int l  = q - ngen;             // 0..63
  const size_t m0 = (size_t)(8 * x + (l & 7)) * FM;
  const size_t n0 = (size_t)(l >> 3) * FN;

  const int lane = t & 63;
  const int wave = t >> 6;             // 0..3
  const int wr = (wave >> 1) * 64;
  const int wc = (wave & 1) * 64;
  const int l15 = lane & 15;
  const int lq  = lane >> 4;
  const int axor = l15 & 3;

  // staging map: A tile 128x32 = 512 chunks8; thread t covers lin = t, t+256:
  // row = lin>>2, phys k-group = lin&3 (XOR-swizzled source k-group sx).
  const int srow = t >> 2;             // 0..63
  const int sx   = (t & 3) ^ (srow & 3);
  const uint16_t* gA = P  + (m0 + srow) * (size_t)NCOLS + sx * 8;
  const uint16_t* gB = xT + (n0 + srow) * (size_t)NCOLS + sx * 8;

  uint16_t* buf0 = sm;
  uint16_t* buf1 = sm + FBUF;
  uint16_t* buf2 = sm + 2 * FBUF;

  auto STAGE = [&](uint16_t* base, int kt){
    const int kk = kt * FK;
    gload16(gA + kk,                            base + t * 8);
    gload16(gA + (size_t)64 * NCOLS + kk,       base + (t + 256) * 8);
    gload16(gB + kk,                            base + 4096 + t * 8);
    gload16(gB + (size_t)64 * NCOLS + kk,       base + 4096 + (t + 256) * 8);
  };

  f32x4 acc[4][4];
  #pragma unroll
  for (int i = 0; i < 4; ++i)
    #pragma unroll
    for (int j = 0; j < 4; ++j)
      #pragma unroll
      for (int r = 0; r < 4; ++r) acc[i][j][r] = 0.0f;

  // prologue: tiles 0,1 (chunk 0) in flight; wait tile 0's 4 loads only.
  wait_flag(&flags[0], GENB);
  STAGE(buf0, 0);
  STAGE(buf1, 1);
  asm volatile("s_waitcnt vmcnt(4)" ::: "memory");
  __builtin_amdgcn_s_barrier();

  uint16_t *pc = buf0, *pn = buf1, *ps = buf2;
  for (int kt = 0; kt < FNT; ++kt){
    if (kt + 2 < FNT){
      if (((kt + 2) & 1) == 0) wait_flag(&flags[(kt + 2) >> 1], GENB);
      STAGE(ps, kt + 2);
    }

    f16x8 af[4], bf[4];
    const int kphys = (lq ^ axor) * 8;
    #pragma unroll
    for (int i = 0; i < 4; ++i)
      af[i] = *reinterpret_cast<const f16x8*>(pc + (wr + i*16 + l15) * FK + kphys);
    #pragma unroll
    for (int j = 0; j < 4; ++j)
      bf[j] = *reinterpret_cast<const f16x8*>(pc + 4096 + (wc + j*16 + l15) * FK + kphys);

    __builtin_amdgcn_s_setprio(1);
    #pragma unroll
    for (int i = 0; i < 4; ++i)
      #pragma unroll
      for (int j = 0; j < 4; ++j)
        acc[i][j] = __builtin_amdgcn_mfma_f32_16x16x32_f16(af[i], bf[j], acc[i][j], 0, 0, 0);
    __builtin_amdgcn_s_setprio(0);

    if (kt + 2 < FNT) asm volatile("s_waitcnt vmcnt(4) lgkmcnt(0)" ::: "memory");
    else              asm volatile("s_waitcnt vmcnt(0) lgkmcnt(0)" ::: "memory");
    __builtin_amdgcn_s_barrier();

    uint16_t* tmp = pc; pc = pn; pn = ps; ps = tmp;
  }

  // epilogue: block row sums from Spart (all gen complete: flags[127] passed).
  float* S_lds = reinterpret_cast<float*>(sm);
  if (t < 128){
    const float* sp = Spart + (m0 + t) * CHUNKS;
    float s = 0.0f;
    #pragma unroll
    for (int j = 0; j < 32; ++j){
      f32x4 v = *reinterpret_cast<const f32x4*>(sp + j * 4);
      s += (v[0] + v[1]) + (v[2] + v[3]);
    }
    S_lds[t] = s;
  }
  __syncthreads();

  #pragma unroll
  for (int i = 0; i < 4; ++i){
    float rinv[4];
    #pragma unroll
    for (int r = 0; r < 4; ++r)
      rinv[r] = 1.0f / S_lds[wr + i*16 + lq*4 + r];
    #pragma unroll
    for (int j = 0; j < 4; ++j){
      const size_t col = n0 + wc + j*16 + l15;
      #pragma unroll
      for (int r = 0; r < 4; ++r){
        const size_t row = m0 + wr + i*16 + lq*4 + r;  // C/D: col=lane&15, row=quad*4+reg
        __builtin_nontemporal_store(acc[i][j][r] * rinv[r], &O[row * DDIM + col]);
      }
    }
  }
}

// ---------------------------------------------------------------------------
extern "C" void kernel_launch(void* const* d_in, const int* in_sizes, int n_in,
                              void* d_out, int out_size, void* d_ws, size_t ws_size,
                              hipStream_t stream)
{
  (void)in_sizes; (void)n_in; (void)out_size;
  const float* x = (const float*)d_in[0];       // [8192][1024] f32; d_in[1] unused
  float* O = (float*)d_out;                     // [8192][1024] f32
  uint8_t* ws = (uint8_t*)d_ws;

  // layout: S[8192] f32 (32KB, fallback) | flags (4KB) | Spart (4MB) | xT | P
  float* S = (float*)ws;
  uint32_t* flags = (uint32_t*)(ws + 32768);
  float* Spart = (float*)(ws + 32768 + 4096);
  const size_t spart_bytes = (size_t)NROWS * CHUNKS * sizeof(float);   // 4 MB
  uint16_t* xT = (uint16_t*)(ws + 32768 + 4096 + spart_bytes);
  const size_t xT_bytes = (size_t)DDIM * NROWS * sizeof(uint16_t);     // 16.8 MB
  uint16_t* P = (uint16_t*)((uint8_t*)xT + xT_bytes);
  const size_t used = 32768 + 4096 + spart_bytes + xT_bytes;
  const size_t avail = ws_size > used ? ws_size - used : 0;

  const size_t fullP = (size_t)NROWS * NCOLS * sizeof(uint16_t);       // 134 MB
  if (avail >= fullP){
    hipMemsetAsync(flags, 0, CHUNKS * sizeof(uint32_t), stream);
    transpose_cast<<<dim3(DDIM/32, NROWS/32), 256, 0, stream>>>(x, xT);
    fused_gen_gemm<<<768, 256, 3 * FBUF * sizeof(uint16_t), stream>>>(P, xT, Spart, flags, O);
  } else {
    transpose_cast<<<dim3(DDIM/32, NROWS/32), 256, 0, stream>>>(x, xT);
    int R = 128;
    for (int r = 4096; r >= 128; r >>= 1)
      if ((size_t)r * NCOLS * sizeof(uint16_t) <= avail){ R = r; break; }
    for (int r0 = 0; r0 < NROWS; r0 += R){
      gen_rows<<<R, 256, 0, stream>>>(P, S, r0);
      gemm_rows<<<dim3(R/BM, DDIM/BN), 256, 0, stream>>>(P, xT, S, r0, O + (size_t)r0 * DDIM);
    }
  }
}

// Round 3
// 403.484 us; speedup vs baseline: 15.5265x; 15.5265x over previous
//
#include <hip/hip_runtime.h>
#include <stdint.h>
#include <stddef.h>

#define NROWS 8192
#define NCOLS 8192       // K dimension = noise-matrix column count
#define DDIM  1024

typedef float  f32x4 __attribute__((ext_vector_type(4)));
typedef _Float16 f16x8 __attribute__((ext_vector_type(8)));

#if __has_builtin(__builtin_amdgcn_exp2f)
#define EXP2F(x) __builtin_amdgcn_exp2f(x)
#else
#define EXP2F(x) exp2f(x)
#endif
#if __has_builtin(__builtin_amdgcn_logf)
#define LOG2F(x) __builtin_amdgcn_logf(x)     // v_log_f32 = log2
#else
#define LOG2F(x) log2f(x)
#endif
#if __has_builtin(__builtin_amdgcn_sqrtf)
#define SQRTF(x) __builtin_amdgcn_sqrtf(x)
#else
#define SQRTF(x) sqrtf(x)
#endif

// ---------------- Threefry-2x32, key = (0, 42) (jax.random.key(42)) ---------
__device__ __forceinline__ uint32_t rotl32(uint32_t x, uint32_t r){
  return (x << r) | (x >> (32u - r));
}

__device__ __forceinline__ void threefry2x32(uint32_t x0, uint32_t x1,
                                             uint32_t& o0, uint32_t& o1){
  const uint32_t k0 = 0u, k1 = 42u;
  const uint32_t k2 = k0 ^ k1 ^ 0x1BD11BDAu;
  x0 += k0; x1 += k1;
#define TF_R(r) { x0 += x1; x1 = rotl32(x1, r); x1 ^= x0; }
  TF_R(13) TF_R(15) TF_R(26) TF_R(6)
  x0 += k1; x1 += k2 + 1u;
  TF_R(17) TF_R(29) TF_R(16) TF_R(24)
  x0 += k2; x1 += k0 + 2u;
  TF_R(13) TF_R(15) TF_R(26) TF_R(6)
  x0 += k0; x1 += k1 + 3u;
  TF_R(17) TF_R(29) TF_R(16) TF_R(24)
  x0 += k1; x1 += k2 + 4u;
  TF_R(13) TF_R(15) TF_R(26) TF_R(6)
  x0 += k2; x1 += k0 + 5u;
#undef TF_R
  o0 = x0; o1 = x1;
}

// Partitionable-threefry element: flat index f -> E' = exp(2*normal)*2^-4.
__device__ __forceinline__ float elemE(uint32_t f){
  uint32_t o0, o1;
  threefry2x32(0u, f, o0, o1);
  const uint32_t b = o0 ^ o1;
  float u = __uint_as_float((b >> 9) | 0x3F800000u) - 1.0f;   // [0,1)
  const float lo = -0.99999994f;                              // nextafter(-1,0)
  float v = fmaf(u, 2.0f, lo);
  v = fmaxf(v, lo);
  const float t1 = fmaf(-v, v, 1.0f);                         // 1 - v^2
  float w = LOG2F(t1) * (-0.69314718f);                       // -ln(1-v^2)
  float p;
  if (w < 5.0f){
    w -= 2.5f;
    p =              3.97426473e-08f;
    p = fmaf(p, w,   4.85465e-07f);
    p = fmaf(p, w,  -4.98283e-06f);
    p = fmaf(p, w,  -6.21053e-06f);
    p = fmaf(p, w,   3.09120e-04f);
    p = fmaf(p, w,  -1.77290e-03f);
    p = fmaf(p, w,  -5.90817e-03f);
    p = fmaf(p, w,   3.48803163e-01f);
    p = fmaf(p, w,   2.12331355e+00f);
  } else {
    w = SQRTF(w) - 3.0f;
    p =             -2.83147363e-04f;
    p = fmaf(p, w,   1.42765560e-04f);
    p = fmaf(p, w,   1.90825981e-03f);
    p = fmaf(p, w,  -5.19500608e-03f);
    p = fmaf(p, w,   8.11688602e-03f);
    p = fmaf(p, w,  -1.07798386e-02f);
    p = fmaf(p, w,   1.33487061e-02f);
    p = fmaf(p, w,   1.41658096e+00f);
    p = fmaf(p, w,   4.00643396e+00f);
  }
  const float m = p * v;                         // sqrt(2)*erfinv(v) ~ N(0,1)
  return EXP2F(fmaf(m, 2.8853900817779268f, -4.0f)); // exp(2m)*2^-4
}

__device__ __forceinline__ uint16_t f2h(float a){
  union { _Float16 h; uint16_t u; } c; c.h = (_Float16)a; return c.u;
}

// ---------------- transpose: x [8192][1024] f32 -> xT f16 -------------------
__global__ __launch_bounds__(256) void transpose_cast(const float* __restrict__ x,
                                                      uint16_t* __restrict__ xT){
  __shared__ float tile[32][33];
  const int tx = threadIdx.x & 31;
  const int ty = threadIdx.x >> 5;          // 0..7
  const int dcol = blockIdx.x * 32;
  const int nrow = blockIdx.y * 32;
  #pragma unroll
  for (int r = 0; r < 32; r += 8)
    tile[ty + r][tx] = x[(size_t)(nrow + ty + r) * DDIM + dcol + tx];
  __syncthreads();
  #pragma unroll
  for (int r = 0; r < 32; r += 8)
    xT[(size_t)(dcol + ty + r) * NROWS + nrow + tx] = f2h(tile[tx][ty + r]);
}

// ---------------- fallback gen (chunked workspace) --------------------------
__global__ __launch_bounds__(256) void gen_rows(uint16_t* __restrict__ P,
                                                float* __restrict__ S, int row0){
  const int gi = row0 + blockIdx.x;
  const uint32_t base = (uint32_t)gi * 8192u;
  const int t = threadIdx.x;
  uint16_t* __restrict__ prow = P + (size_t)blockIdx.x * NCOLS;
  float acc = 0.0f;
  #pragma unroll
  for (int g = 0; g < 4; ++g){
    const uint32_t j0 = (uint32_t)(g * 2048) + ((uint32_t)t << 3);
    float e[8];
    #pragma unroll
    for (int i = 0; i < 8; ++i){ e[i] = elemE(base + j0 + (uint32_t)i); acc += e[i]; }
    f16x8 pk;
    #pragma unroll
    for (int i = 0; i < 8; ++i) pk[i] = (_Float16)e[i];
    *reinterpret_cast<f16x8*>(prow + j0) = pk;
  }
  #pragma unroll
  for (int off = 32; off > 0; off >>= 1) acc += __shfl_down(acc, off, 64);
  __shared__ float sm[4];
  if ((t & 63) == 0) sm[t >> 6] = acc;
  __syncthreads();
  if (t == 0) S[gi] = (sm[0] + sm[1]) + (sm[2] + sm[3]);
}

typedef const __attribute__((address_space(1))) void GAS;
typedef __attribute__((address_space(3))) void LAS;

__device__ __forceinline__ void gload16(const void* g, void* l){
  __builtin_amdgcn_global_load_lds((GAS*)g, (LAS*)l, 16, 0, 0);
}

// ---------------- fallback GEMM (chunked path): 128x128, 1-phase ------------
#define BM 128
#define BN 128
#define BK 64

__global__ __launch_bounds__(256, 3) void gemm_rows(
    const uint16_t* __restrict__ P, const uint16_t* __restrict__ xT,
    const float* __restrict__ S, int row0, float* __restrict__ O)
{
  __shared__ uint16_t smem[16384];      // As[128][64] | Bs[128][64]
  uint16_t* As = smem;
  uint16_t* Bs = smem + 8192;

  const int tid  = threadIdx.x;
  const int lane = tid & 63;
  const int wave = tid >> 6;
  const int wr = (wave >> 1) * 64;
  const int wc = (wave & 1) * 64;
  const int l15 = lane & 15;
  const int lq  = lane >> 4;

  const size_t m0 = (size_t)blockIdx.x * BM;
  const size_t n0 = (size_t)blockIdx.y * BN;

  const int srow = tid >> 3;                    // 0..31
  const int sx   = (tid & 7) ^ (srow & 7);      // swizzled source k-group
  const uint16_t* gA = P  + (m0 + srow) * (size_t)NCOLS + sx * 8;
  const uint16_t* gB = xT + (n0 + srow) * (size_t)NCOLS + sx * 8;

  f32x4 acc[4][4];
  #pragma unroll
  for (int i = 0; i < 4; ++i)
    #pragma unroll
    for (int j = 0; j < 4; ++j)
      #pragma unroll
      for (int q = 0; q < 4; ++q) acc[i][j][q] = 0.0f;

  const int axor = l15 & 7;

  for (int k0 = 0; k0 < NCOLS; k0 += BK){
    #pragma unroll
    for (int r = 0; r < 4; ++r)
      gload16(gA + (size_t)(32 * r) * NCOLS + k0, As + (tid + 256 * r) * 8);
    #pragma unroll
    for (int r = 0; r < 4; ++r)
      gload16(gB + (size_t)(32 * r) * NCOLS + k0, Bs + (tid + 256 * r) * 8);
    __syncthreads();
    #pragma unroll
    for (int ks = 0; ks < 2; ++ks){
      const int kphys = ((lq + 4 * ks) ^ axor) * 8;
      f16x8 af[4], bfrag[4];
      #pragma unroll
      for (int i = 0; i < 4; ++i)
        af[i] = *reinterpret_cast<const f16x8*>(As + (wr + i*16 + l15) * BK + kphys);
      #pragma unroll
      for (int j = 0; j < 4; ++j)
        bfrag[j] = *reinterpret_cast<const f16x8*>(Bs + (wc + j*16 + l15) * BK + kphys);
      #pragma unroll
      for (int i = 0; i < 4; ++i)
        #pragma unroll
        for (int j = 0; j < 4; ++j)
          acc[i][j] = __builtin_amdgcn_mfma_f32_16x16x32_f16(af[i], bfrag[j], acc[i][j], 0, 0, 0);
    }
    __syncthreads();
  }

  #pragma unroll
  for (int i = 0; i < 4; ++i){
    float rinv[4];
    #pragma unroll
    for (int r = 0; r < 4; ++r)
      rinv[r] = 1.0f / S[row0 + m0 + wr + i*16 + lq*4 + r];
    #pragma unroll
    for (int j = 0; j < 4; ++j){
      const size_t col = n0 + wc + j*16 + l15;
      #pragma unroll
      for (int r = 0; r < 4; ++r){
        const size_t row = m0 + wr + i*16 + lq*4 + r;
        O[row * DDIM + col] = acc[i][j][r] * rinv[r];
      }
    }
  }
}

// ===================== FUSED producer/consumer kernel v3 ====================
// Grid = 768 x 256 thr, 48 KB LDS each -> exactly 3 blocks/CU, all resident
// => no deadlock. Roles: b%3==2 -> gen (256 blocks, 32 rows each);
// else gemm (512 blocks, 128x128 tile).
//
// Sync redesign (round-2 post-mortem): NO contended RMW, NO fences/cache-inv.
//  - producer g writes P/Spart with agent-scope RELAXED atomic stores (sc1:
//    write-through to IC, never dirty in a private L2), drains vmcnt(0),
//    barrier, then t0 relaxed-stores prog[g*32] = chunks_done (single writer,
//    own 128B line -> zero contention).
//  - consumer (m0) depends on exactly 4 producers g0..g0+3; spins with
//    RELAXED agent loads (IC reads, no invalidates). P data lines are
//    first-touched only after the flag => no stale copy can exist locally;
//    plain cached reads are safe, and the 8 n-tile sharers reuse L2.
#define FM 128
#define FN 128
#define FK 32
#define FNT (NCOLS / FK)      // 256 K-tiles
#define FBUF 8192             // uint16 elems per buffer (A 4096 | B 4096)
#define PCH 64                // column chunks of 128 cols
#define PROGPAD 32            // uint32 stride between producer counters (128B)

__global__ __launch_bounds__(256, 3) void fused_gen_gemm(
    uint16_t* __restrict__ P,          // [8192][8192] f16 (unnormalized E')
    const uint16_t* __restrict__ xT,   // [1024][8192] f16
    float* __restrict__ Spart,         // [8192][PCH] f32 per-chunk row sums
    uint32_t* prog,                    // [256*PROGPAD] per-producer progress
    float* __restrict__ O)             // [8192][1024] f32
{
  const int b = blockIdx.x;
  const int t = threadIdx.x;

  if (b % 3 == 2){
    // ------------------------- gen role (256 blocks) -------------------------
    const int g   = b / 3;           // 0..255 -> rows [32g, 32g+32)
    const int rl  = t >> 3;          // 0..31 local row
    const int sub = t & 7;           // 8 threads per row, 16 cols each
    const int row = g * 32 + rl;
    uint16_t* prow = P + (size_t)row * NCOLS;
    const uint32_t fb = (uint32_t)row * 8192u;
    for (int kc = 0; kc < PCH; ++kc){
      const uint32_t f0 = fb + (uint32_t)(kc * 128 + sub * 16);
      float acc = 0.0f;
      #pragma unroll
      for (int h = 0; h < 2; ++h){
        float e[8];
        #pragma unroll
        for (int i = 0; i < 8; ++i){ e[i] = elemE(f0 + (uint32_t)(h*8 + i)); acc += e[i]; }
        union { f16x8 v; uint64_t u[2]; } cv;
        #pragma unroll
        for (int i = 0; i < 8; ++i) cv.v[i] = (_Float16)e[i];
        uint64_t* dst = reinterpret_cast<uint64_t*>(prow + kc * 128 + sub * 16 + h * 8);
        __hip_atomic_store(dst,     cv.u[0], __ATOMIC_RELAXED, __HIP_MEMORY_SCOPE_AGENT);
        __hip_atomic_store(dst + 1, cv.u[1], __ATOMIC_RELAXED, __HIP_MEMORY_SCOPE_AGENT);
      }
      acc += __shfl_down(acc, 4, 8);
      acc += __shfl_down(acc, 2, 8);
      acc += __shfl_down(acc, 1, 8);
      if (sub == 0)
        __hip_atomic_store(&Spart[(size_t)row * PCH + kc], acc,
                           __ATOMIC_RELAXED, __HIP_MEMORY_SCOPE_AGENT);
      asm volatile("s_waitcnt vmcnt(0)" ::: "memory");  // this wave's stores at IC
      __syncthreads();                                  // => all waves' stores at IC
      if (t == 0)
        __hip_atomic_store(&prog[(size_t)g * PROGPAD], (uint32_t)(kc + 1),
                           __ATOMIC_RELAXED, __HIP_MEMORY_SCOPE_AGENT);
    }
    return;
  }

  // ------------------------- gemm role (512 blocks) --------------------------
  extern __shared__ uint16_t sm[];     // 3 * FBUF uint16 = 48 KB

  // XCD-rank mapping (perf heuristic only): XCD x = b&7 owns m-panels
  // [8x, 8x+8), all 8 n-tiles; l = gemm rank among this XCD's blocks.
  const int x  = b & 7;
  const int q  = b >> 3;               // 0..95
  const int rx = ((2 - (x % 3)) * 2) % 3;
  const int ngen = (q > rx) ? ((q - rx - 1) / 3 + 1) : 0;
  const int l  = q - ngen;             // 0..63
  const size_t m0 = (size_t)(8 * x + (l & 7)) * FM;
  const size_t n0 = (size_t)(l >> 3) * FN;

  const int g0 = (int)(m0 >> 5);       // first of 4 producers for these rows

  auto wait4 = [&](uint32_t target){
    int guard = 0;
    while (true){
      uint32_t a = __hip_atomic_load(&prog[(size_t)(g0    ) * PROGPAD], __ATOMIC_RELAXED, __HIP_MEMORY_SCOPE_AGENT);
      uint32_t c = __hip_atomic_load(&prog[(size_t)(g0 + 1) * PROGPAD], __ATOMIC_RELAXED, __HIP_MEMORY_SCOPE_AGENT);
      uint32_t d = __hip_atomic_load(&prog[(size_t)(g0 + 2) * PROGPAD], __ATOMIC_RELAXED, __HIP_MEMORY_SCOPE_AGENT);
      uint32_t e = __hip_atomic_load(&prog[(size_t)(g0 + 3) * PROGPAD], __ATOMIC_RELAXED, __HIP_MEMORY_SCOPE_AGENT);
      uint32_t mn = min(min(a, c), min(d, e));
      if (mn >= target) break;
      __builtin_amdgcn_s_sleep(2);
      if (++guard > (1 << 22)) break;  // safety valve; never hit if correct
    }
  };

  const int lane = t & 63;
  const int wave = t >> 6;             // 0..3
  const int wr = (wave >> 1) * 64;
  const int wc = (wave & 1) * 64;
  const int l15 = lane & 15;
  const int lq  = lane >> 4;
  const int axor = l15 & 3;

  const int srow = t >> 2;             // 0..63
  const int sx   = (t & 3) ^ (srow & 3);
  const uint16_t* gA = P  + (m0 + srow) * (size_t)NCOLS + sx * 8;
  const uint16_t* gB = xT + (n0 + srow) * (size_t)NCOLS + sx * 8;

  uint16_t* buf0 = sm;
  uint16_t* buf1 = sm + FBUF;
  uint16_t* buf2 = sm + 2 * FBUF;

  auto STAGE = [&](uint16_t* base, int kt){
    const int kk = kt * FK;
    gload16(gA + kk,                            base + t * 8);
    gload16(gA + (size_t)64 * NCOLS + kk,       base + (t + 256) * 8);
    gload16(gB + kk,                            base + 4096 + t * 8);
    gload16(gB + (size_t)64 * NCOLS + kk,       base + 4096 + (t + 256) * 8);
  };

  f32x4 acc[4][4];
  #pragma unroll
  for (int i = 0; i < 4; ++i)
    #pragma unroll
    for (int j = 0; j < 4; ++j)
      #pragma unroll
      for (int r = 0; r < 4; ++r) acc[i][j][r] = 0.0f;

  // prologue: chunk 0 ready -> stage tiles 0,1; wait tile 0's 4 loads only.
  wait4(1);
  STAGE(buf0, 0);
  STAGE(buf1, 1);
  asm volatile("s_waitcnt vmcnt(4)" ::: "memory");
  __builtin_amdgcn_s_barrier();

  uint16_t *pc = buf0, *pn = buf1, *ps = buf2;
  for (int kt = 0; kt < FNT; ++kt){
    if (kt + 2 < FNT){
      const int kt2 = kt + 2;
      if ((kt2 & 3) == 0) wait4((uint32_t)(kt2 >> 2) + 1);  // chunk kt2/4 done
      STAGE(ps, kt2);
    }

    f16x8 af[4], bf[4];
    const int kphys = (lq ^ axor) * 8;
    #pragma unroll
    for (int i = 0; i < 4; ++i)
      af[i] = *reinterpret_cast<const f16x8*>(pc + (wr + i*16 + l15) * FK + kphys);
    #pragma unroll
    for (int j = 0; j < 4; ++j)
      bf[j] = *reinterpret_cast<const f16x8*>(pc + 4096 + (wc + j*16 + l15) * FK + kphys);

    __builtin_amdgcn_s_setprio(1);
    #pragma unroll
    for (int i = 0; i < 4; ++i)
      #pragma unroll
      for (int j = 0; j < 4; ++j)
        acc[i][j] = __builtin_amdgcn_mfma_f32_16x16x32_f16(af[i], bf[j], acc[i][j], 0, 0, 0);
    __builtin_amdgcn_s_setprio(0);

    if (kt + 2 < FNT) asm volatile("s_waitcnt vmcnt(4) lgkmcnt(0)" ::: "memory");
    else              asm volatile("s_waitcnt vmcnt(0) lgkmcnt(0)" ::: "memory");
    __builtin_amdgcn_s_barrier();

    uint16_t* tmp = pc; pc = pn; pn = ps; ps = tmp;
  }

  // epilogue: row sums from Spart (these rows' producers fully done: waited
  // target 64 at kt2=252, covering all PCH chunks).
  float* S_lds = reinterpret_cast<float*>(sm);
  if (t < 128){
    const float* sp = Spart + (m0 + t) * PCH;
    float s = 0.0f;
    #pragma unroll
    for (int j = 0; j < PCH / 4; ++j){
      f32x4 v = *reinterpret_cast<const f32x4*>(sp + j * 4);
      s += (v[0] + v[1]) + (v[2] + v[3]);
    }
    S_lds[t] = s;
  }
  __syncthreads();

  #pragma unroll
  for (int i = 0; i < 4; ++i){
    float rinv[4];
    #pragma unroll
    for (int r = 0; r < 4; ++r)
      rinv[r] = 1.0f / S_lds[wr + i*16 + lq*4 + r];
    #pragma unroll
    for (int j = 0; j < 4; ++j){
      const size_t col = n0 + wc + j*16 + l15;
      #pragma unroll
      for (int r = 0; r < 4; ++r){
        const size_t row = m0 + wr + i*16 + lq*4 + r;  // C/D: col=lane&15, row=quad*4+reg
        __builtin_nontemporal_store(acc[i][j][r] * rinv[r], &O[row * DDIM + col]);
      }
    }
  }
}

// ---------------------------------------------------------------------------
extern "C" void kernel_launch(void* const* d_in, const int* in_sizes, int n_in,
                              void* d_out, int out_size, void* d_ws, size_t ws_size,
                              hipStream_t stream)
{
  (void)in_sizes; (void)n_in; (void)out_size;
  const float* x = (const float*)d_in[0];       // [8192][1024] f32; d_in[1] unused
  float* O = (float*)d_out;                     // [8192][1024] f32
  uint8_t* ws = (uint8_t*)d_ws;

  // layout: S (32KB, fallback) | prog (32KB) | Spart [8192][64] f32 (2MB) | xT | P
  float* S = (float*)ws;
  uint32_t* prog = (uint32_t*)(ws + 32768);
  const size_t prog_bytes = 256 * PROGPAD * sizeof(uint32_t);          // 32 KB
  float* Spart = (float*)(ws + 32768 + prog_bytes);
  const size_t spart_bytes = (size_t)NROWS * PCH * sizeof(float);      // 2 MB
  uint16_t* xT = (uint16_t*)((uint8_t*)Spart + spart_bytes);
  const size_t xT_bytes = (size_t)DDIM * NROWS * sizeof(uint16_t);     // 16.8 MB
  uint16_t* P = (uint16_t*)((uint8_t*)xT + xT_bytes);
  const size_t used = 32768 + prog_bytes + spart_bytes + xT_bytes;
  const size_t avail = ws_size > used ? ws_size - used : 0;

  const size_t fullP = (size_t)NROWS * NCOLS * sizeof(uint16_t);       // 134 MB
  if (avail >= fullP){
    hipMemsetAsync(prog, 0, prog_bytes, stream);
    transpose_cast<<<dim3(DDIM/32, NROWS/32), 256, 0, stream>>>(x, xT);
    fused_gen_gemm<<<768, 256, 3 * FBUF * sizeof(uint16_t), stream>>>(P, xT, Spart, prog, O);
  } else {
    transpose_cast<<<dim3(DDIM/32, NROWS/32), 256, 0, stream>>>(x, xT);
    int R = 128;
    for (int r = 4096; r >= 128; r >>= 1)
      if ((size_t)r * NCOLS * sizeof(uint16_t) <= avail){ R = r; break; }
    for (int r0 = 0; r0 < NROWS; r0 += R){
      gen_rows<<<R, 256, 0, stream>>>(P, S, r0);
      gemm_rows<<<dim3(R/BM, DDIM/BN), 256, 0, stream>>>(P, xT, S, r0, O + (size_t)r0 * DDIM);
    }
  }
}